// Round 3
// baseline (12571.580 us; speedup 1.0000x reference)
//
#include <hip/hip_runtime.h>
#include <hip/hip_bf16.h>
#include <math.h>

#define BH 64
#define NSEQ 8192
#define DHEAD 64
#define M 128
#define LGRP 64
#define NC 4
#define CHUNK (NSEQ / NC)   // 2048
#define NSWEEP 10
#define RCOND 1.52587890625e-4   // 10 * 128 * eps_f32  (jax f32 pinv rtol)

// ---------------- Kernel A: landmarks (f64 pooling, q scaled by 1/8) ----------------
__global__ __launch_bounds__(64) void lm_kernel(const float* __restrict__ q,
                                                const float* __restrict__ k,
                                                double* __restrict__ ql64,
                                                double* __restrict__ kl64,
                                                float* __restrict__ klf32) {
    int idx = blockIdx.x;            // 0..16383
    int tensor = idx >> 13;          // 0 = q, 1 = k
    int g = idx & 8191;
    int head = g >> 7, m = g & 127;
    int d = threadIdx.x;             // 64 threads = 64 dims
    const float* src = tensor ? k : q;
    const float* base = src + ((size_t)head * NSEQ + (size_t)m * LGRP) * DHEAD + d;
    double s = 0.0;
    #pragma unroll 8
    for (int r = 0; r < LGRP; ++r) s += (double)base[(size_t)r * DHEAD];
    s *= (1.0 / LGRP);
    if (!tensor) s *= 0.125;         // q / sqrt(64)
    size_t o = (size_t)head * M * DHEAD + (size_t)m * DHEAD + d;
    if (!tensor) { ql64[o] = s; }
    else         { kl64[o] = s; klf32[o] = (float)s; }
}

// ---------------- Kernel B: S = softmax(ql @ kl^T) f64, stored COLUMN-major ----------------
__global__ __launch_bounds__(256) void s_kernel(const double* __restrict__ ql64,
                                                const double* __restrict__ kl64,
                                                double* __restrict__ Sg) {
    extern __shared__ double Sl[];   // [128][129]
    int head = blockIdx.x;
    int t = threadIdx.x;
    const double* qb = ql64 + (size_t)head * M * DHEAD;
    const double* kb = kl64 + (size_t)head * M * DHEAD;
    for (int e = t; e < M * M; e += 256) {
        int i = e >> 7, j = e & 127;
        double s = 0.0;
        #pragma unroll 8
        for (int d = 0; d < DHEAD; ++d) s += qb[i * DHEAD + d] * kb[j * DHEAD + d];
        Sl[i * 129 + j] = s;
    }
    __syncthreads();
    if (t < M) {   // row softmax (max-subtract mirrors reference)
        double mx = -1e300;
        for (int j = 0; j < M; ++j) mx = fmax(mx, Sl[t * 129 + j]);
        double sum = 0.0;
        for (int j = 0; j < M; ++j) { double e = exp(Sl[t * 129 + j] - mx); Sl[t * 129 + j] = e; sum += e; }
        double inv = 1.0 / sum;
        for (int j = 0; j < M; ++j) Sl[t * 129 + j] *= inv;
    }
    __syncthreads();
    // store column-major: Sg[col*128+row] = S[row][col]
    for (int e = t; e < M * M; e += 256) {
        int col = e >> 7, row = e & 127;
        Sg[(size_t)head * M * M + e] = Sl[row * 129 + col];
    }
}

// ---------------- Kernel C: one-sided Jacobi SVD of S; emit W = U * diag(1/sigma^2) --------
// pinv(S) = S^T U Sigma^-2 U^T (on kept dirs) => apply as S^T * W * W^T with W = U/sigma.
__global__ __launch_bounds__(256) void jacobi_kernel(const double* __restrict__ Sg,
                                                     double* __restrict__ Wcol,
                                                     double* __restrict__ Wrow) {
    extern __shared__ double G[];    // columns: col c at G + c*129 (pad vs bank conflicts)
    __shared__ double norms2[M];
    __shared__ double maxn2_s;
    int head = blockIdx.x;
    int t = threadIdx.x;
    const double* Sh = Sg + (size_t)head * M * M;
    for (int e = t; e < M * M; e += 256) G[(e >> 7) * 129 + (e & 127)] = Sh[e];
    __syncthreads();
    int grp = t >> 2, sub = t & 3;   // 64 pair-groups x 4 threads
    for (int sweep = 0; sweep < NSWEEP; ++sweep) {
        for (int r = 0; r < 127; ++r) {
            int ca, cb;
            if (grp == 0) { ca = 127; cb = r; }
            else { ca = (r + grp) % 127; cb = (r - grp + 127) % 127; }
            double* gA = G + ca * 129;
            double* gB = G + cb * 129;
            double a = 0.0, b = 0.0, c = 0.0;
            for (int x = sub; x < M; x += 4) {
                double va = gA[x], vb = gB[x];
                a += va * va; b += vb * vb; c += va * vb;
            }
            a += __shfl_xor(a, 1); a += __shfl_xor(a, 2);
            b += __shfl_xor(b, 1); b += __shfl_xor(b, 2);
            c += __shfl_xor(c, 1); c += __shfl_xor(c, 2);
            if (c != 0.0) {
                double zeta = (b - a) / (2.0 * c);
                double tt = (zeta >= 0.0 ? 1.0 : -1.0) / (fabs(zeta) + sqrt(1.0 + zeta * zeta));
                double cs = 1.0 / sqrt(1.0 + tt * tt);
                double sn = cs * tt;
                for (int x = sub; x < M; x += 4) {
                    double va = gA[x], vb = gB[x];
                    gA[x] = cs * va - sn * vb;
                    gB[x] = sn * va + cs * vb;
                }
            }
            __syncthreads();
        }
    }
    // column norms^2 = sigma^2
    {
        int cc = t >> 1, hh = t & 1;
        double s = 0.0;
        for (int x = hh * 64; x < hh * 64 + 64; ++x) { double v = G[cc * 129 + x]; s += v * v; }
        s += __shfl_xor(s, 1);
        if (hh == 0) norms2[cc] = s;
    }
    __syncthreads();
    if (t < 64) {
        double mm = fmax(norms2[t], norms2[t + 64]);
        for (int off = 32; off > 0; off >>= 1) mm = fmax(mm, __shfl_down(mm, off));
        if (t == 0) maxn2_s = mm;
    }
    __syncthreads();
    double cut2 = maxn2_s * (RCOND * RCOND);   // (rcond*sigma1)^2 cutoff on sigma^2
    for (int e = t; e < M * M; e += 256) {
        int cc = e >> 7, rr = e & 127;
        double n2 = norms2[cc];
        double w = (n2 > cut2) ? G[cc * 129 + rr] / n2 : 0.0;   // w_c = u_c / sigma_c
        Wcol[(size_t)head * M * M + (size_t)cc * M + rr] = w;
        Wrow[(size_t)head * M * M + (size_t)rr * M + cc] = w;
    }
}

// ---------------- Kernel D: partial B@v in f64 ----------------
__global__ __launch_bounds__(256) void bv_kernel(const float* __restrict__ k,
                                                 const float* __restrict__ v,
                                                 const double* __restrict__ ql64,
                                                 double* __restrict__ numd,
                                                 double* __restrict__ dend) {
    int head = blockIdx.x >> 2;   // NC = 4
    int chunk = blockIdx.x & 3;
    int t = threadIdx.x;
    int m = t >> 1, h = t & 1;
    double ql[32];
    const double* qb = ql64 + ((size_t)head * M + m) * DHEAD + h * 32;
    #pragma unroll
    for (int d = 0; d < 32; ++d) ql[d] = qb[d];
    double acc[32];
    #pragma unroll
    for (int d = 0; d < 32; ++d) acc[d] = 0.0;
    double dacc = 0.0;
    const float* kb = k + ((size_t)head * NSEQ + (size_t)chunk * CHUNK) * DHEAD + h * 32;
    const float* vb = v + ((size_t)head * NSEQ + (size_t)chunk * CHUNK) * DHEAD + h * 32;
    for (int key = 0; key < CHUNK; ++key) {
        const float4* kr = (const float4*)(kb + (size_t)key * DHEAD);
        double z = 0.0;
        #pragma unroll
        for (int c = 0; c < 8; ++c) {
            float4 kk = kr[c];
            z += ql[4 * c]     * (double)kk.x;
            z += ql[4 * c + 1] * (double)kk.y;
            z += ql[4 * c + 2] * (double)kk.z;
            z += ql[4 * c + 3] * (double)kk.w;
        }
        z += __shfl_xor(z, 1);        // combine half-dots
        double e = exp(z);            // |z| < ~1, no shift needed
        dacc += e;
        const float4* vr = (const float4*)(vb + (size_t)key * DHEAD);
        #pragma unroll
        for (int c = 0; c < 8; ++c) {
            float4 vv = vr[c];
            acc[4 * c]     += e * (double)vv.x;
            acc[4 * c + 1] += e * (double)vv.y;
            acc[4 * c + 2] += e * (double)vv.z;
            acc[4 * c + 3] += e * (double)vv.w;
        }
    }
    size_t ob = (((size_t)head * NC + chunk) * M + m) * DHEAD + h * 32;
    #pragma unroll
    for (int d = 0; d < 32; ++d) numd[ob + d] = acc[d];
    if (h == 0) dend[((size_t)head * NC + chunk) * M + m] = dacc;
}

// ---------------- Kernel E: reduce partials -> Bv (f64) ----------------
__global__ __launch_bounds__(256) void bvreduce_kernel(const double* __restrict__ numd,
                                                       const double* __restrict__ dend,
                                                       double* __restrict__ Xg) {
    __shared__ double dsum[M];
    int head = blockIdx.x;
    int t = threadIdx.x;
    if (t < M) {
        double s = 0.0;
        for (int c = 0; c < NC; ++c) s += dend[((size_t)head * NC + c) * M + t];
        dsum[t] = s;
    }
    __syncthreads();
    for (int e = t; e < M * DHEAD; e += 256) {
        int m = e >> 6;
        double s = 0.0;
        for (int c = 0; c < NC; ++c) s += numd[((size_t)head * NC + c) * (M * DHEAD) + e];
        Xg[(size_t)head * M * DHEAD + e] = s / dsum[m];
    }
}

// ---------------- Kernel F: Y[i][:] = sum_r Mcol_i[r] * X[r][:]  (applies M^T) ------------
__global__ __launch_bounds__(256) void colapply_kernel(const double* __restrict__ Mg,
                                                       const double* __restrict__ Xg,
                                                       double* __restrict__ Yg) {
    __shared__ double xs[M * 65];
    int head = blockIdx.x;
    int t = threadIdx.x;
    for (int e = t; e < M * DHEAD; e += 256) xs[(e >> 6) * 65 + (e & 63)] = Xg[(size_t)head * M * DHEAD + e];
    __syncthreads();
    int i = t >> 1, hf = t & 1;
    const double* mc = Mg + (size_t)head * M * M + (size_t)i * M;
    double acc[32];
    #pragma unroll
    for (int dd = 0; dd < 32; ++dd) acc[dd] = 0.0;
    for (int r = 0; r < M; ++r) {
        double mv = mc[r];
        #pragma unroll 8
        for (int dd = 0; dd < 32; ++dd) acc[dd] += mv * xs[r * 65 + hf * 32 + dd];
    }
    double* ob = Yg + (size_t)head * M * DHEAD + (size_t)i * DHEAD + hf * 32;
    #pragma unroll
    for (int dd = 0; dd < 32; ++dd) ob[dd] = acc[dd];
}

// ---------------- Kernel G: out = softmax(q @ kl^T) @ ABv ----------------
__global__ __launch_bounds__(256) void out_kernel(const float* __restrict__ q,
                                                  const float* __restrict__ klf32,
                                                  const double* __restrict__ ABv,
                                                  float* __restrict__ out) {
    __shared__ float kls[M * DHEAD];   // 32 KB
    int head = blockIdx.x >> 6;
    int tile = blockIdx.x & 63;
    int t = threadIdx.x;               // 128 rows x 2 halves
    int r = t >> 1, h = t & 1;
    for (int e = t; e < M * DHEAD; e += 256)
        kls[e] = klf32[(size_t)head * M * DHEAD + e];
    __syncthreads();
    size_t row = (size_t)head * NSEQ + (size_t)tile * M + r;
    const float4* qr = (const float4*)(q + row * DHEAD + h * 32);
    float qv[32];
    #pragma unroll
    for (int c = 0; c < 8; ++c) {
        float4 t4 = qr[c];
        qv[4 * c]     = t4.x * 0.125f;
        qv[4 * c + 1] = t4.y * 0.125f;
        qv[4 * c + 2] = t4.z * 0.125f;
        qv[4 * c + 3] = t4.w * 0.125f;
    }
    double acc[32];
    #pragma unroll
    for (int d = 0; d < 32; ++d) acc[d] = 0.0;
    float dacc = 0.f;
    const double* ab = ABv + (size_t)head * M * DHEAD + h * 32;
    for (int m = 0; m < M; ++m) {
        const float4* kr = (const float4*)(kls + m * DHEAD + h * 32);
        float z = 0.f;
        #pragma unroll
        for (int c = 0; c < 8; ++c) {
            float4 kk = kr[c];
            z += qv[4 * c]     * kk.x + qv[4 * c + 1] * kk.y
               + qv[4 * c + 2] * kk.z + qv[4 * c + 3] * kk.w;
        }
        z += __shfl_xor(z, 1);
        float e = __expf(z);
        dacc += e;
        double ed = (double)e;
        const double2* ar = (const double2*)(ab + (size_t)m * DHEAD);
        #pragma unroll
        for (int c = 0; c < 16; ++c) {
            double2 av = ar[c];
            acc[2 * c]     += ed * av.x;
            acc[2 * c + 1] += ed * av.y;
        }
    }
    double inv = 1.0 / (double)dacc;
    float* ob = out + row * DHEAD + h * 32;
    #pragma unroll
    for (int d = 0; d < 32; ++d) ob[d] = (float)(acc[d] * inv);
}

extern "C" void kernel_launch(void* const* d_in, const int* in_sizes, int n_in,
                              void* d_out, int out_size, void* d_ws, size_t ws_size,
                              hipStream_t stream) {
    const float* q = (const float*)d_in[0];
    const float* k = (const float*)d_in[1];
    const float* v = (const float*)d_in[2];
    float* out = (float*)d_out;
    char* ws = (char*)d_ws;
    // ws layout (<= 57,147,392 bytes)
    double* ql64  = (double*)(ws + 0);           //  4 MB
    double* kl64  = (double*)(ws + 4194304);     //  4 MB
    float*  klf32 = (float*)(ws + 8388608);      //  2 MB
    double* Sg    = (double*)(ws + 10485760);    //  8 MB (S column-major per head)
    double* Wcol  = (double*)(ws + 18874368);    //  8 MB
    double* Wrow  = (double*)(ws + 27262976);    //  8 MB
    double* Yg    = (double*)(ws + 35651584);    //  4 MB (Bv/t2/ABv ping)
    double* numd  = (double*)(ws + 39845888);    // 16 MB (also reused as Xg after reduce)
    double* dend  = (double*)(ws + 56623104);    // 256 KB
    double* Xg    = numd;                        // alias: numd dead after bvreduce

    lm_kernel<<<16384, 64, 0, stream>>>(q, k, ql64, kl64, klf32);
    s_kernel<<<BH, 256, 128 * 129 * 8, stream>>>(ql64, kl64, Sg);
    jacobi_kernel<<<BH, 256, 128 * 129 * 8, stream>>>(Sg, Wcol, Wrow);
    bv_kernel<<<BH * NC, 256, 0, stream>>>(k, v, ql64, numd, dend);
    bvreduce_kernel<<<BH, 256, 0, stream>>>(numd, dend, Yg);      // Yg = Bv
    colapply_kernel<<<BH, 256, 0, stream>>>(Wcol, Yg, Xg);        // Xg = W^T Bv
    colapply_kernel<<<BH, 256, 0, stream>>>(Wrow, Xg, Yg);        // Yg = W W^T Bv
    colapply_kernel<<<BH, 256, 0, stream>>>(Sg, Yg, Xg);          // Xg = S^T W W^T Bv = ABv
    out_kernel<<<BH * 64, 256, 0, stream>>>(q, klf32, Xg, out);
}

// Round 4
// 4947.794 us; speedup vs baseline: 2.5408x; 2.5408x over previous
//
#include <hip/hip_runtime.h>
#include <hip/hip_bf16.h>
#include <math.h>

#define BH 64
#define NSEQ 8192
#define DHEAD 64
#define M 128
#define LGRP 64
#define NC 8
#define CHUNK (NSEQ / NC)   // 1024
#define NSWEEP 10
#define RCOND 1.52587890625e-4   // 10 * 128 * eps_f32  (jax f32 pinv rtol)

// ---------------- Kernel A: landmarks (f64 pooling, q scaled by 1/8) ----------------
__global__ __launch_bounds__(64) void lm_kernel(const float* __restrict__ q,
                                                const float* __restrict__ k,
                                                double* __restrict__ ql64,
                                                double* __restrict__ kl64,
                                                float* __restrict__ qlf32,
                                                float* __restrict__ klf32) {
    int idx = blockIdx.x;            // 0..16383
    int tensor = idx >> 13;          // 0 = q, 1 = k
    int g = idx & 8191;
    int head = g >> 7, m = g & 127;
    int d = threadIdx.x;
    const float* src = tensor ? k : q;
    const float* base = src + ((size_t)head * NSEQ + (size_t)m * LGRP) * DHEAD + d;
    double s = 0.0;
    #pragma unroll 8
    for (int r = 0; r < LGRP; ++r) s += (double)base[(size_t)r * DHEAD];
    s *= (1.0 / LGRP);
    if (!tensor) s *= 0.125;         // q / sqrt(64)
    size_t o = (size_t)head * M * DHEAD + (size_t)m * DHEAD + d;
    if (!tensor) { ql64[o] = s; qlf32[o] = (float)s; }
    else         { kl64[o] = s; klf32[o] = (float)s; }
}

// ---------------- Kernel B: S = softmax(ql @ kl^T) f64, stored COLUMN-major ----------------
__global__ __launch_bounds__(512) void s_kernel(const double* __restrict__ ql64,
                                                const double* __restrict__ kl64,
                                                double* __restrict__ Sg) {
    extern __shared__ double lds[];      // qlds[8192] | klds[8192]  (128 KB)
    double* qlds = lds;
    double* klds = lds + M * DHEAD;
    int head = blockIdx.x;
    int t = threadIdx.x;
    const double2* qg = (const double2*)(ql64 + (size_t)head * M * DHEAD);
    const double2* kg = (const double2*)(kl64 + (size_t)head * M * DHEAD);
    for (int e = t; e < M * DHEAD / 2; e += 512) {
        ((double2*)qlds)[e] = qg[e];
        ((double2*)klds)[e] = kg[e];
    }
    __syncthreads();
    int tr = t >> 4, tc = t & 15;        // rows 4tr..+4, cols 8tc..+8
    double acc[4][8];
    #pragma unroll
    for (int i = 0; i < 4; ++i)
        #pragma unroll
        for (int j = 0; j < 8; ++j) acc[i][j] = 0.0;
    for (int dc = 0; dc < DHEAD; dc += 4) {
        double qreg[4][4], kreg[8][4];
        #pragma unroll
        for (int i = 0; i < 4; ++i)
            #pragma unroll
            for (int d = 0; d < 4; ++d) qreg[i][d] = qlds[(4 * tr + i) * DHEAD + dc + d];
        #pragma unroll
        for (int j = 0; j < 8; ++j)
            #pragma unroll
            for (int d = 0; d < 4; ++d) kreg[j][d] = klds[(8 * tc + j) * DHEAD + dc + d];
        #pragma unroll
        for (int i = 0; i < 4; ++i)
            #pragma unroll
            for (int j = 0; j < 8; ++j)
                #pragma unroll
                for (int d = 0; d < 4; ++d) acc[i][j] += qreg[i][d] * kreg[j][d];
    }
    double* So = Sg + (size_t)head * M * M;
    #pragma unroll
    for (int i = 0; i < 4; ++i) {
        double mx = acc[i][0];
        #pragma unroll
        for (int j = 1; j < 8; ++j) mx = fmax(mx, acc[i][j]);
        mx = fmax(mx, __shfl_xor(mx, 1));
        mx = fmax(mx, __shfl_xor(mx, 2));
        mx = fmax(mx, __shfl_xor(mx, 4));
        mx = fmax(mx, __shfl_xor(mx, 8));
        double sum = 0.0;
        #pragma unroll
        for (int j = 0; j < 8; ++j) { acc[i][j] = exp(acc[i][j] - mx); sum += acc[i][j]; }
        sum += __shfl_xor(sum, 1); sum += __shfl_xor(sum, 2);
        sum += __shfl_xor(sum, 4); sum += __shfl_xor(sum, 8);
        double inv = 1.0 / sum;
        #pragma unroll
        for (int j = 0; j < 8; ++j)
            So[(size_t)(8 * tc + j) * M + 4 * tr + i] = acc[i][j] * inv;   // col-major
    }
}

// ---------------- Kernel C: one-sided Jacobi SVD; emit Wcol[cc*M+rr] = u[rr][cc]/sigma_cc^2-norm
// 512 thr = 64 pairs x 8. Pair columns cached in regs; unpadded col-major (bank = f(x) only);
// per-pair x-rotation (sub + 4*grp) gives exactly 4 lanes/bank-pair = byte-floor.
__global__ __launch_bounds__(512) void jacobi_kernel(const double* __restrict__ Sg,
                                                     double* __restrict__ Wcol) {
    extern __shared__ double G[];        // [col][x], stride 128, 128 KB
    __shared__ double norms2[M];
    __shared__ double maxn2_s;
    int head = blockIdx.x;
    int t = threadIdx.x;
    const double2* Sh2 = (const double2*)(Sg + (size_t)head * M * M);
    for (int e = t; e < M * M / 2; e += 512) ((double2*)G)[e] = Sh2[e];
    __syncthreads();
    int grp = t >> 3, sub = t & 7;
    int xoff[16];
    #pragma unroll
    for (int j = 0; j < 16; ++j) xoff[j] = (sub + 4 * grp + 8 * j) & 127;
    for (int sweep = 0; sweep < NSWEEP; ++sweep) {
        for (int r = 0; r < 127; ++r) {
            int ca, cb;
            if (grp == 0) { ca = 127; cb = r; }
            else { ca = (r + grp) % 127; cb = (r + 127 - grp) % 127; }
            double* gA = G + ca * 128;
            double* gB = G + cb * 128;
            double va[16], vb[16];
            #pragma unroll
            for (int j = 0; j < 16; ++j) va[j] = gA[xoff[j]];
            #pragma unroll
            for (int j = 0; j < 16; ++j) vb[j] = gB[xoff[j]];
            double a = 0.0, b = 0.0, c = 0.0;
            #pragma unroll
            for (int j = 0; j < 16; ++j) { a += va[j] * va[j]; b += vb[j] * vb[j]; c += va[j] * vb[j]; }
            a += __shfl_xor(a, 1); a += __shfl_xor(a, 2); a += __shfl_xor(a, 4);
            b += __shfl_xor(b, 1); b += __shfl_xor(b, 2); b += __shfl_xor(b, 4);
            c += __shfl_xor(c, 1); c += __shfl_xor(c, 2); c += __shfl_xor(c, 4);
            if (c * c > 1e-20 * a * b) {   // skip angle < ~1e-10 (no-op at f64 level)
                double zeta = (b - a) / (2.0 * c);
                double tt = (zeta >= 0.0 ? 1.0 : -1.0) / (fabs(zeta) + sqrt(1.0 + zeta * zeta));
                double cs = 1.0 / sqrt(1.0 + tt * tt);
                double sn = cs * tt;
                #pragma unroll
                for (int j = 0; j < 16; ++j) {
                    double na = cs * va[j] - sn * vb[j];
                    double nb = sn * va[j] + cs * vb[j];
                    gA[xoff[j]] = na;
                    gB[xoff[j]] = nb;
                }
            }
            __syncthreads();
        }
    }
    {   // column norms^2 = sigma^2
        int cc = t >> 2, qd = t & 3;
        double s = 0.0;
        #pragma unroll 8
        for (int x = qd * 32; x < qd * 32 + 32; ++x) { double vv = G[cc * 128 + x]; s += vv * vv; }
        s += __shfl_xor(s, 1); s += __shfl_xor(s, 2);
        if (qd == 0) norms2[cc] = s;
    }
    __syncthreads();
    if (t < 64) {
        double mm = fmax(norms2[t], norms2[t + 64]);
        for (int off = 32; off > 0; off >>= 1) mm = fmax(mm, __shfl_down(mm, off));
        if (t == 0) maxn2_s = mm;
    }
    __syncthreads();
    double cut2 = maxn2_s * (RCOND * RCOND);
    for (int e = t; e < M * M; e += 512) {
        int cc = e >> 7, rr = e & 127;
        double n2 = norms2[cc];
        Wcol[(size_t)head * M * M + e] = (n2 > cut2) ? G[cc * 128 + rr] / n2 : 0.0;
    }
}

// ---------------- Kernel D: partial B@v -- f32 dot/exp + blocked f64 flush ----------------
__global__ __launch_bounds__(256) void bv_kernel(const float* __restrict__ k,
                                                 const float* __restrict__ v,
                                                 const float* __restrict__ qlf32,
                                                 double* __restrict__ numd,
                                                 double* __restrict__ dend) {
    int head = blockIdx.x >> 3;   // NC = 8
    int chunk = blockIdx.x & 7;
    int t = threadIdx.x;
    int m = t >> 1, h = t & 1;
    float ql[32];
    const float* qb = qlf32 + ((size_t)head * M + m) * DHEAD + h * 32;
    #pragma unroll
    for (int d = 0; d < 32; ++d) ql[d] = qb[d];
    float acc32[32]; double acc64[32];
    #pragma unroll
    for (int d = 0; d < 32; ++d) { acc32[d] = 0.f; acc64[d] = 0.0; }
    float dacc32 = 0.f; double dacc64 = 0.0;
    const float* kb = k + ((size_t)head * NSEQ + (size_t)chunk * CHUNK) * DHEAD + h * 32;
    const float* vb = v + ((size_t)head * NSEQ + (size_t)chunk * CHUNK) * DHEAD + h * 32;
    for (int key = 0; key < CHUNK; ++key) {
        const float4* kr = (const float4*)(kb + (size_t)key * DHEAD);
        float z = 0.f;
        #pragma unroll
        for (int c = 0; c < 8; ++c) {
            float4 kk = kr[c];
            z += ql[4 * c] * kk.x + ql[4 * c + 1] * kk.y + ql[4 * c + 2] * kk.z + ql[4 * c + 3] * kk.w;
        }
        z += __shfl_xor(z, 1);        // combine half-dots (both lanes same z)
        float e = __expf(z);          // |z| < ~1
        dacc32 += e;
        const float4* vr = (const float4*)(vb + (size_t)key * DHEAD);
        #pragma unroll
        for (int c = 0; c < 8; ++c) {
            float4 vv = vr[c];
            acc32[4 * c]     += e * vv.x;
            acc32[4 * c + 1] += e * vv.y;
            acc32[4 * c + 2] += e * vv.z;
            acc32[4 * c + 3] += e * vv.w;
        }
        if (((key + 1) & 127) == 0) {  // f64 flush every 128 keys
            #pragma unroll
            for (int d = 0; d < 32; ++d) { acc64[d] += (double)acc32[d]; acc32[d] = 0.f; }
            dacc64 += (double)dacc32; dacc32 = 0.f;
        }
    }
    size_t ob = (((size_t)head * NC + chunk) * M + m) * DHEAD + h * 32;
    #pragma unroll
    for (int d = 0; d < 32; ++d) numd[ob + d] = acc64[d];
    if (h == 0) dend[((size_t)head * NC + chunk) * M + m] = dacc64;
}

// ---------------- Kernel E: fused  Bv reduce -> W^T -> W -> S^T  (all f64, ABv out f32) ----
__global__ __launch_bounds__(512) void apply_kernel(const double* __restrict__ numd,
                                                    const double* __restrict__ dend,
                                                    const double* __restrict__ Wcol,
                                                    const double* __restrict__ Sg,
                                                    float* __restrict__ ABvf32) {
    extern __shared__ double lds[];
    double* A_ = lds;                 // [128][66]
    double* B_ = lds + M * 66;
    __shared__ double dsum[M];
    int head = blockIdx.x;
    int t = threadIdx.x;
    if (t < M) {
        double s = 0.0;
        #pragma unroll
        for (int c = 0; c < NC; ++c) s += dend[((size_t)head * NC + c) * M + t];
        dsum[t] = s;
    }
    __syncthreads();
    for (int e = t; e < M * DHEAD; e += 512) {
        int mm = e >> 6;
        double s = 0.0;
        #pragma unroll
        for (int c = 0; c < NC; ++c) s += numd[((size_t)head * NC + c) * (M * DHEAD) + e];
        A_[mm * 66 + (e & 63)] = s / dsum[mm];
    }
    __syncthreads();
    int i = t >> 3, qd = t & 7;       // rows i, i+64; dims qd*8..+8
    const double* Wb = Wcol + (size_t)head * M * M;
    const double* Sb = Sg + (size_t)head * M * M;
    {   // stage 1: B = W^T A ; (W^T)[i][r] = Wcol[i*M + r]
        double a0[8], a1[8];
        #pragma unroll
        for (int d = 0; d < 8; ++d) { a0[d] = 0.0; a1[d] = 0.0; }
        for (int r = 0; r < M; ++r) {
            double m0 = Wb[(size_t)i * M + r];
            double m1 = Wb[(size_t)(i + 64) * M + r];
            #pragma unroll
            for (int d = 0; d < 8; ++d) {
                double xv = A_[r * 66 + qd * 8 + d];
                a0[d] += m0 * xv; a1[d] += m1 * xv;
            }
        }
        #pragma unroll
        for (int d = 0; d < 8; ++d) {
            B_[i * 66 + qd * 8 + d] = a0[d];
            B_[(i + 64) * 66 + qd * 8 + d] = a1[d];
        }
    }
    __syncthreads();
    {   // stage 2: A = W B ; W[i][r] = Wcol[r*M + i]
        double a0[8], a1[8];
        #pragma unroll
        for (int d = 0; d < 8; ++d) { a0[d] = 0.0; a1[d] = 0.0; }
        for (int r = 0; r < M; ++r) {
            double m0 = Wb[(size_t)r * M + i];
            double m1 = Wb[(size_t)r * M + i + 64];
            #pragma unroll
            for (int d = 0; d < 8; ++d) {
                double xv = B_[r * 66 + qd * 8 + d];
                a0[d] += m0 * xv; a1[d] += m1 * xv;
            }
        }
        #pragma unroll
        for (int d = 0; d < 8; ++d) {
            A_[i * 66 + qd * 8 + d] = a0[d];
            A_[(i + 64) * 66 + qd * 8 + d] = a1[d];
        }
    }
    __syncthreads();
    {   // stage 3: ABv = S^T A ; (S^T)[i][r] = S[r][i] = Sg[i*M + r] (col-major)
        double a0[8], a1[8];
        #pragma unroll
        for (int d = 0; d < 8; ++d) { a0[d] = 0.0; a1[d] = 0.0; }
        for (int r = 0; r < M; ++r) {
            double m0 = Sb[(size_t)i * M + r];
            double m1 = Sb[(size_t)(i + 64) * M + r];
            #pragma unroll
            for (int d = 0; d < 8; ++d) {
                double xv = A_[r * 66 + qd * 8 + d];
                a0[d] += m0 * xv; a1[d] += m1 * xv;
            }
        }
        float* ob = ABvf32 + (size_t)head * M * DHEAD;
        #pragma unroll
        for (int d = 0; d < 8; ++d) {
            ob[i * DHEAD + qd * 8 + d] = (float)a0[d];
            ob[(i + 64) * DHEAD + qd * 8 + d] = (float)a1[d];
        }
    }
}

// ---------------- Kernel F: out = softmax(q @ kl^T) @ ABv  (all f32, 2-row tiling) --------
__global__ __launch_bounds__(512) void out_kernel(const float* __restrict__ q,
                                                  const float* __restrict__ klf32,
                                                  const float* __restrict__ ABvf32,
                                                  float* __restrict__ out) {
    __shared__ float kls[M * DHEAD];    // 32 KB
    __shared__ float avs[M * DHEAD];    // 32 KB
    int head = blockIdx.x >> 4;
    int tile = blockIdx.x & 15;         // 16 tiles x 512 rows
    int t = threadIdx.x;
    for (int e = t; e < M * DHEAD; e += 512) {
        kls[e] = klf32[(size_t)head * M * DHEAD + e];
        avs[e] = ABvf32[(size_t)head * M * DHEAD + e];
    }
    __syncthreads();
    int rl = t >> 1, h = t & 1;
    size_t row0 = (size_t)head * NSEQ + (size_t)tile * 512 + rl;
    size_t row1 = row0 + 256;
    const float4* qr0 = (const float4*)(q + row0 * DHEAD + h * 32);
    const float4* qr1 = (const float4*)(q + row1 * DHEAD + h * 32);
    float4 qa[8], qb[8];
    #pragma unroll
    for (int c = 0; c < 8; ++c) {
        float4 x = qr0[c];
        x.x *= 0.125f; x.y *= 0.125f; x.z *= 0.125f; x.w *= 0.125f;
        qa[c] = x;
        float4 y = qr1[c];
        y.x *= 0.125f; y.y *= 0.125f; y.z *= 0.125f; y.w *= 0.125f;
        qb[c] = y;
    }
    float acc0[32], acc1[32];
    #pragma unroll
    for (int d = 0; d < 32; ++d) { acc0[d] = 0.f; acc1[d] = 0.f; }
    float d0 = 0.f, d1 = 0.f;
    for (int mm = 0; mm < M; ++mm) {
        const float4* kr = (const float4*)(kls + mm * DHEAD + h * 32);
        float z0 = 0.f, z1 = 0.f;
        #pragma unroll
        for (int c = 0; c < 8; ++c) {
            float4 kk = kr[c];
            z0 += qa[c].x * kk.x + qa[c].y * kk.y + qa[c].z * kk.z + qa[c].w * kk.w;
            z1 += qb[c].x * kk.x + qb[c].y * kk.y + qb[c].z * kk.z + qb[c].w * kk.w;
        }
        z0 += __shfl_xor(z0, 1);
        z1 += __shfl_xor(z1, 1);
        float e0 = __expf(z0), e1 = __expf(z1);
        d0 += e0; d1 += e1;
        const float4* ar = (const float4*)(avs + mm * DHEAD + h * 32);
        #pragma unroll
        for (int c = 0; c < 8; ++c) {
            float4 av = ar[c];
            acc0[4 * c]     += e0 * av.x; acc0[4 * c + 1] += e0 * av.y;
            acc0[4 * c + 2] += e0 * av.z; acc0[4 * c + 3] += e0 * av.w;
            acc1[4 * c]     += e1 * av.x; acc1[4 * c + 1] += e1 * av.y;
            acc1[4 * c + 2] += e1 * av.z; acc1[4 * c + 3] += e1 * av.w;
        }
    }
    float i0 = 1.f / d0, i1 = 1.f / d1;
    float* o0 = out + row0 * DHEAD + h * 32;
    float* o1 = out + row1 * DHEAD + h * 32;
    #pragma unroll
    for (int d = 0; d < 32; ++d) { o0[d] = acc0[d] * i0; o1[d] = acc1[d] * i1; }
}

extern "C" void kernel_launch(void* const* d_in, const int* in_sizes, int n_in,
                              void* d_out, int out_size, void* d_ws, size_t ws_size,
                              hipStream_t stream) {
    const float* q = (const float*)d_in[0];
    const float* k = (const float*)d_in[1];
    const float* v = (const float*)d_in[2];
    float* out = (float*)d_out;
    char* ws = (char*)d_ws;
    // ws layout (57,147,392 bytes total)
    double* numd  = (double*)(ws + 0);            // 32 MB  [0 .. 33,554,432)
    double* ql64  = (double*)(ws + 0);            //  4 MB  (aliases numd; dead before bv)
    double* kl64  = (double*)(ws + 4194304);      //  4 MB  (aliases numd; dead before bv)
    double* dend  = (double*)(ws + 33554432);     //  512 KB
    float*  qlf32 = (float*)(ws + 34078720);      //  2 MB
    float*  klf32 = (float*)(ws + 36175872);      //  2 MB
    double* Sg    = (double*)(ws + 38273024);     //  8 MB  (S column-major per head)
    double* Wcol  = (double*)(ws + 46661632);     //  8 MB
    float*  ABvf32= (float*)(ws + 55050240);      //  2 MB  (ends 57,147,392)

    lm_kernel<<<16384, 64, 0, stream>>>(q, k, ql64, kl64, qlf32, klf32);
    s_kernel<<<BH, 512, 2 * M * DHEAD * 8, stream>>>(ql64, kl64, Sg);
    jacobi_kernel<<<BH, 512, M * M * 8, stream>>>(Sg, Wcol);
    bv_kernel<<<BH * NC, 256, 0, stream>>>(k, v, qlf32, numd, dend);
    apply_kernel<<<BH, 512, 2 * M * 66 * 8, stream>>>(numd, dend, Wcol, Sg, ABvf32);
    out_kernel<<<BH * 16, 512, 0, stream>>>(q, klf32, ABvf32, out);
}